// Round 7
// baseline (1317.956 us; speedup 1.0000x reference)
//
#include <hip/hip_runtime.h>
#include <hip/hip_bf16.h>

// Problem constants (B, C, H, W) = (8, 1024, 64, 64); N = H*W = 4096.
#define BATCH 8
#define CH    1024
#define NN    4096

typedef __attribute__((ext_vector_type(8))) short bf16x8;   // 8 bf16 = 4 VGPRs
typedef __attribute__((ext_vector_type(4))) float f32x4;
using bf16 = __hip_bfloat16;

struct bhalf4 { bf16 x, y, z, w; };               // 8 bytes

__device__ __forceinline__ unsigned short f2bfu(float f) {
  bf16 h = __float2bfloat16(f);
  return *reinterpret_cast<unsigned short*>(&h);
}

// ---------------------------------------------------------------------------
// Vectorized transpose + cast: in [B][C][N] fp32 -> out [B][N][C] bf16.
// (unchanged from round-6 passing version)
// ---------------------------------------------------------------------------
template <bool ASQ>
__global__ __launch_bounds__(256) void transpose_cast_v(
    const float* __restrict__ in_all, bf16* __restrict__ out_all,
    float* __restrict__ asq_all) {
  int bz = blockIdx.z;
  const float* in = in_all + (size_t)bz * CH * NN;
  bf16* out = out_all + (size_t)bz * NN * CH;

  __shared__ float tile[64][65];
  __shared__ float sqb[16][64];

  int n0 = blockIdx.x * 64;
  int c0 = blockIdx.y * 64;
  int t = threadIdx.x;
  int nc = t & 15;
  int cr = t >> 4;

  float4 sq4 = make_float4(0.f, 0.f, 0.f, 0.f);
#pragma unroll
  for (int i = 0; i < 4; ++i) {
    int c = cr + i * 16;
    float4 v = *(const float4*)(in + (size_t)(c0 + c) * NN + n0 + nc * 4);
    tile[c][nc * 4 + 0] = v.x;
    tile[c][nc * 4 + 1] = v.y;
    tile[c][nc * 4 + 2] = v.z;
    tile[c][nc * 4 + 3] = v.w;
    if (ASQ) {
      sq4.x += v.x * v.x; sq4.y += v.y * v.y;
      sq4.z += v.z * v.z; sq4.w += v.w * v.w;
    }
  }
  if (ASQ) {
    sqb[cr][nc * 4 + 0] = sq4.x;
    sqb[cr][nc * 4 + 1] = sq4.y;
    sqb[cr][nc * 4 + 2] = sq4.z;
    sqb[cr][nc * 4 + 3] = sq4.w;
  }
  __syncthreads();
  if (ASQ && t < 64) {
    float s = 0.f;
#pragma unroll
    for (int i = 0; i < 16; ++i) s += sqb[i][t];
    atomicAdd(&asq_all[(size_t)bz * NN + n0 + t], s);
  }
  int cchunk = t & 7;
  int nb = t >> 3;
#pragma unroll
  for (int p = 0; p < 2; ++p) {
    int n = nb + p * 32;
    bf16x8 o;
#pragma unroll
    for (int j = 0; j < 8; ++j)
      o[j] = (short)f2bfu(tile[cchunk * 8 + j][n]);
    *(bf16x8*)(out + (size_t)(n0 + n) * CH + c0 + cchunk * 8) = o;
  }
}

// ---------------------------------------------------------------------------
// Plain cast: [B*C*N] fp32 -> bf16 flat.
// ---------------------------------------------------------------------------
__global__ __launch_bounds__(256) void convert_cast(
    const float4* __restrict__ in, bhalf4* __restrict__ out) {
  size_t i = (size_t)blockIdx.x * 256 + threadIdx.x;
  float4 v = in[i];
  bhalf4 o;
  o.x = __float2bfloat16(v.x);
  o.y = __float2bfloat16(v.y);
  o.z = __float2bfloat16(v.z);
  o.w = __float2bfloat16(v.w);
  out[i] = o;
}

// ---------------------------------------------------------------------------
// 128x128 / BK=32 / 3-buffer GEMM (C = A * B^T) with FRAGMENT READ-AHEAD.
// 4 waves (2x2), per-wave 64x64 output, 48 KiB LDS -> 3 blocks/CU.
//
// Round-6 showed reads and MFMA serialize by construction (read -> barrier
// -> lgkm0 -> MFMA), giving MfmaUtil 31.6% = MFMA/(MFMA+LDS+L2). This round
// overlaps them: tile t+1's ds_reads are ISSUED in tile t's iteration,
// BEFORE tile t's MFMA cluster (no wait between them); the consuming MFMA
// (next iteration) sits behind an explicit lgkmcnt(0)+sched_barrier(0)
// (rule 18). Two named frag sets (a0/b0, a1/b1), loop pair-unrolled so all
// register indices are compile-time (rule 20).
//
// Schedule per tile t (one barrier per tile):
//   BARR ; lgkm0+schedbar (frags(t) ready)
//   stage(t+2)->buf[(t+2)%3] ; vmcnt(4)  [tail: vmcnt(0)]  (t+1's DMA landed)
//   ds_read frags(t+1) from buf[(t+1)%3]     (no wait -- overlaps MFMA)
//   MFMA(frags(t)) x16
// Race audit:
//   * stage(t+2) overwrites tile t-1's buffer; t-1's frag reads were
//     lgkm0-drained at tile t-1's top = 1 full barrier earlier. SAFE.
//   * frags(t+1) read from buf[(t+1)%3]; that buffer is next staged with
//     tile t+4 at iteration t+2, 2 barriers after their lgkm0 drain. SAFE.
//   * vmcnt(4) after stage leaves only t+2's 4 loads in flight => t+1's
//     staged data landed before its ds_reads issue. Tail drains to 0.
// ---------------------------------------------------------------------------
#define BARR() __builtin_amdgcn_s_barrier()
#define PRIO(x) __builtin_amdgcn_s_setprio(x)
#define LDS_FENCE() do {                                      \
    asm volatile("s_waitcnt lgkmcnt(0)" ::: "memory");        \
    __builtin_amdgcn_sched_barrier(0);                        \
  } while (0)
#define MEM_FENCE() do {                                      \
    asm volatile("" ::: "memory");                            \
    __builtin_amdgcn_sched_barrier(0);                        \
  } while (0)

__device__ __forceinline__ void gload16(const bf16* g, bf16* l) {
  __builtin_amdgcn_global_load_lds(
      (const __attribute__((address_space(1))) void*)g,
      (__attribute__((address_space(3))) void*)l, 16, 0, 0);
}

template <int K, int MODE, int TM, int TN>
__global__ __launch_bounds__(256, 3) void gemm_s3(
    const bf16* __restrict__ Aall, const bf16* __restrict__ Ball,
    bf16* __restrict__ Pall, float* __restrict__ Oall,
    const float* __restrict__ asq_all, float* __restrict__ rsum_all) {
  constexpr int NT = K / 32;           // even for all instantiations
  constexpr int TPB = TM * TN;
  constexpr int NWG = TPB * BATCH;
  constexpr int GRP = 8;

  // XCD-bijective swizzle (NWG % 8 == 0) + L2 grouping.
  int lid = blockIdx.x;
  int swz = (lid & 7) * (NWG >> 3) + (lid >> 3);
  int bz  = swz / TPB;
  int rem = swz - bz * TPB;
  int g  = rem / (GRP * TN);
  int r2 = rem - g * (GRP * TN);
  int bx = r2 / GRP;
  int by = g * GRP + (r2 & (GRP - 1));

  const bf16* Ab = Aall + (size_t)bz * TM * 128 * K + (size_t)(by * 128) * K;
  const bf16* Bb = Ball + (size_t)bz * TN * 128 * K + (size_t)(bx * 128) * K;

  __shared__ bf16 As[3][128 * 32];     // 24 KiB
  __shared__ bf16 Bs[3][128 * 32];     // 24 KiB
  bf16* const AsB = &As[0][0];
  bf16* const BsB = &Bs[0][0];

  int tid = threadIdx.x;
  int wv = tid >> 6, lane = tid & 63;
  int fl = lane & 15, quad = lane >> 4;
  int wr = wv >> 1, wc = wv & 1;

  // Staging addresses (pre-swizzled global source; linear LDS dest).
  int r0 = tid >> 2;
  int c0 = (tid & 3) ^ ((r0 >> 1) & 3);
  int r1 = (256 + tid) >> 2;
  int c1 = ((256 + tid) & 3) ^ ((r1 >> 1) & 3);
  const bf16* gA0 = Ab + (size_t)r0 * K + c0 * 8;
  const bf16* gA1 = Ab + (size_t)r1 * K + c1 * 8;
  const bf16* gB0 = Bb + (size_t)r0 * K + c0 * 8;
  const bf16* gB1 = Bb + (size_t)r1 * K + c1 * 8;
  int ls0 = wv * 512;
  int ls1 = 2048 + wv * 512;

  // Fragment-read offsets (swizzle: chunk ^= (row>>1)&3, lane-constant).
  int kq = (quad ^ ((fl >> 1) & 3)) * 8;
  int aoff = (wr * 64 + fl) * 32 + kq;
  int boff = (wc * 64 + fl) * 32 + kq;

  f32x4 acc[4][4] = {};
  bf16x8 a0[4], b0[4], a1[4], b1[4];

#define STAGE2(SB) do {                                                       \
    bf16* da = AsB + (SB) * 4096;                                             \
    bf16* db = BsB + (SB) * 4096;                                             \
    gload16(gA0, da + ls0); gload16(gA1, da + ls1);                           \
    gload16(gB0, db + ls0); gload16(gB1, db + ls1);                           \
    gA0 += 32; gA1 += 32; gB0 += 32; gB1 += 32;                               \
  } while (0)

#define RDFRAGS(AF, BF, CB) do {                                              \
    const bf16* Ac_ = AsB + (CB) * 4096;                                      \
    const bf16* Bc_ = BsB + (CB) * 4096;                                      \
    _Pragma("unroll")                                                         \
    for (int mi_ = 0; mi_ < 4; ++mi_)                                         \
      AF[mi_] = *(const bf16x8*)(Ac_ + aoff + mi_ * 512);                     \
    _Pragma("unroll")                                                         \
    for (int nj_ = 0; nj_ < 4; ++nj_)                                         \
      BF[nj_] = *(const bf16x8*)(Bc_ + boff + nj_ * 512);                     \
  } while (0)

#define DOMFMA(AF, BF) do {                                                   \
    PRIO(1);                                                                  \
    _Pragma("unroll")                                                         \
    for (int mi_ = 0; mi_ < 4; ++mi_)                                         \
      _Pragma("unroll")                                                       \
      for (int nj_ = 0; nj_ < 4; ++nj_)                                       \
        acc[mi_][nj_] = __builtin_amdgcn_mfma_f32_16x16x32_bf16(              \
            AF[mi_], BF[nj_], acc[mi_][nj_], 0, 0, 0);                        \
    PRIO(0);                                                                  \
  } while (0)

  // Prologue: stage tiles 0,1; drain tile 0; pre-issue frags(0).
  STAGE2(0);
  STAGE2(1);
  asm volatile("s_waitcnt vmcnt(4)" ::: "memory");
  BARR();
  RDFRAGS(a0, b0, 0);

  int cb = 0;                           // buffer of tile t
  for (int t = 0; t < NT; t += 2) {
    int nb = cb + 1; if (nb == 3) nb = 0;
    int s2 = nb + 1; if (s2 == 3) s2 = 0;

    // ---- even tile t: consume (a0,b0); prefetch frags(t+1) ----
    BARR();
    asm volatile("s_waitcnt lgkmcnt(0)" ::: "memory");
    __builtin_amdgcn_sched_barrier(0);
    if (t + 2 < NT) {
      STAGE2(s2);
      asm volatile("s_waitcnt vmcnt(4)" ::: "memory");
    } else {
      asm volatile("s_waitcnt vmcnt(0)" ::: "memory");
    }
    RDFRAGS(a1, b1, nb);                // t+1 < NT always (NT even)
    DOMFMA(a0, b0);

    // ---- odd tile t+1: consume (a1,b1); prefetch frags(t+2) ----
    BARR();
    asm volatile("s_waitcnt lgkmcnt(0)" ::: "memory");
    __builtin_amdgcn_sched_barrier(0);
    if (t + 3 < NT) {
      STAGE2(cb);                       // (t+3) % 3 == cb
      asm volatile("s_waitcnt vmcnt(4)" ::: "memory");
    } else {
      asm volatile("s_waitcnt vmcnt(0)" ::: "memory");
    }
    if (t + 2 < NT) RDFRAGS(a0, b0, s2);
    DOMFMA(a1, b1);

    cb = s2;
  }
#undef STAGE2
#undef RDFRAGS
#undef DOMFMA

  // All staging drained (tail vmcnt(0)) and reads consumed; sync before
  // reusing LDS as epilogue scratch.
  __syncthreads();

  // ---- Epilogue: wave-private 16x64 LDS transpose -> 16B stores ----
  int colbase = bx * 128 + wc * 64;
  int rowg0 = by * 128 + wr * 64;

  if constexpr (MODE == 0) {
    const float* asq = asq_all + (size_t)bz * NN;
    float* rsum = rsum_all + (size_t)bz * NN;
    bf16* P = Pall + (size_t)bz * NN * NN;
    short* scr = (short*)AsB + wv * 1024;   // 16x64 bf16 per wave

    float aq[4];
#pragma unroll
    for (int nj = 0; nj < 4; ++nj) aq[nj] = asq[colbase + nj * 16 + fl];

    float rs[4][4];
#pragma unroll
    for (int mi = 0; mi < 4; ++mi)
#pragma unroll
      for (int r = 0; r < 4; ++r) rs[mi][r] = 0.f;

#pragma unroll
    for (int mi = 0; mi < 4; ++mi) {
#pragma unroll
      for (int nj = 0; nj < 4; ++nj)
#pragma unroll
        for (int r = 0; r < 4; ++r) {
          int row = (quad << 2) + r;
          float e = __expf((2.f * acc[mi][nj][r] - aq[nj]) * 0.03125f);
          rs[mi][r] += e;
          int chunk = (nj * 2 + (fl >> 3)) ^ (row & 7);
          scr[row * 64 + chunk * 8 + (fl & 7)] = (short)f2bfu(e);
        }
      LDS_FENCE();
#pragma unroll
      for (int p = 0; p < 2; ++p) {
        int row = (p << 3) + (lane >> 3);
        int c = lane & 7;
        int chunk = c ^ (row & 7);
        bf16x8 v = *(const bf16x8*)(scr + row * 64 + chunk * 8);
        *(bf16x8*)(P + (size_t)(rowg0 + mi * 16 + row) * NN + colbase + c * 8) = v;
      }
      MEM_FENCE();
    }
#pragma unroll
    for (int mi = 0; mi < 4; ++mi)
#pragma unroll
      for (int r = 0; r < 4; ++r) {
        float v = rs[mi][r];
        v += __shfl_xor(v, 1);
        v += __shfl_xor(v, 2);
        v += __shfl_xor(v, 4);
        v += __shfl_xor(v, 8);
        if (fl == 0)
          atomicAdd(&rsum[rowg0 + mi * 16 + (quad << 2) + r], v);
      }
  } else {
    float* Co = Oall + (size_t)bz * 2 * CH * NN;     // first CV block
    const float* rsum = rsum_all + (size_t)bz * NN;
    float* scr = (float*)AsB + wv * 1024;            // 16x64 f32 per wave

    float inv[4];
#pragma unroll
    for (int nj = 0; nj < 4; ++nj) inv[nj] = 1.f / rsum[colbase + nj * 16 + fl];

#pragma unroll
    for (int mi = 0; mi < 4; ++mi) {
#pragma unroll
      for (int nj = 0; nj < 4; ++nj)
#pragma unroll
        for (int r = 0; r < 4; ++r) {
          int row = (quad << 2) + r;
          int chunk = (nj * 4 + (fl >> 2)) ^ (row & 15);
          scr[row * 64 + chunk * 4 + (fl & 3)] = acc[mi][nj][r] * inv[nj];
        }
      LDS_FENCE();
#pragma unroll
      for (int p = 0; p < 4; ++p) {
        int row = (p << 2) + (lane >> 4);
        int c = lane & 15;
        int chunk = c ^ (row & 15);
        f32x4 v = *(const f32x4*)(scr + row * 64 + chunk * 4);
        *(f32x4*)(Co + (size_t)(rowg0 + mi * 16 + row) * NN + colbase + c * 4) = v;
      }
      MEM_FENCE();
    }
  }
}

// ---------------------------------------------------------------------------
// Copy curr_value into the second half of each batch's output channel block.
// ---------------------------------------------------------------------------
__global__ __launch_bounds__(256) void copy_curr(
    const float4* __restrict__ src, float4* __restrict__ dst) {
  size_t idx = (size_t)blockIdx.x * 256 + threadIdx.x;
  size_t b = idx >> 20;
  size_t r = idx & 1048575;
  dst[b * 2097152 + 1048576 + r] = src[idx];
}

// ---------------------------------------------------------------------------
extern "C" void kernel_launch(void* const* d_in, const int* in_sizes, int n_in,
                              void* d_out, int out_size, void* d_ws, size_t ws_size,
                              hipStream_t stream) {
  const float* prev_key   = (const float*)d_in[0];
  const float* prev_value = (const float*)d_in[1];
  const float* curr_key   = (const float*)d_in[2];
  const float* curr_value = (const float*)d_in[3];
  float* out = (float*)d_out;

  char* ws = (char*)d_ws;
  bf16* P     = (bf16*)(ws);                        // 256 MB [B][N][N]
  bf16* mk_t  = (bf16*)(ws + 268435456u);           //  64 MB [B][N][C]
  bf16* qk_t  = (bf16*)(ws + 335544320u);           //  64 MB [B][N][C]
  bf16* mo_b  = (bf16*)(ws + 402653184u);           //  64 MB [B][C][N]
  float* a_sq = (float*)(ws + 469762048u);          // 128 KB [B][N]
  float* rsum = a_sq + (size_t)BATCH * NN;          // 128 KB [B][N]

  hipMemsetAsync(a_sq, 0, 2ull * BATCH * NN * sizeof(float), stream);

  transpose_cast_v<true><<<dim3(NN / 64, CH / 64, BATCH), 256, 0, stream>>>(
      prev_key, mk_t, a_sq);
  transpose_cast_v<false><<<dim3(NN / 64, CH / 64, BATCH), 256, 0, stream>>>(
      curr_key, qk_t, nullptr);
  convert_cast<<<(size_t)BATCH * CH * NN / 4 / 256, 256, 0, stream>>>(
      (const float4*)prev_value, (bhalf4*)mo_b);

  // GEMM1: ab = qk_t * mk_t^T  (M=N=4096, K=1024), fused exp + rowsum.
  gemm_s3<CH, 0, 32, 32><<<dim3(32 * 32 * BATCH), dim3(256), 0, stream>>>(
      qk_t, mk_t, P, nullptr, a_sq, rsum);

  // GEMM2: mem = mo * P^T  (M=1024, N=4096, K=4096), fused 1/rowsum.
  gemm_s3<NN, 1, 8, 32><<<dim3(8 * 32 * BATCH), dim3(256), 0, stream>>>(
      mo_b, P, nullptr, out, nullptr, rsum);

  copy_curr<<<(size_t)BATCH * CH * NN / 4 / 256, 256, 0, stream>>>(
      (const float4*)curr_value, (float4*)out);
}

// Round 8
// 1186.537 us; speedup vs baseline: 1.1108x; 1.1108x over previous
//
#include <hip/hip_runtime.h>
#include <hip/hip_bf16.h>

// Problem constants (B, C, H, W) = (8, 1024, 64, 64); N = H*W = 4096.
#define BATCH 8
#define CH    1024
#define NN    4096

typedef __attribute__((ext_vector_type(8))) short bf16x8;   // 8 bf16 = 4 VGPRs
typedef __attribute__((ext_vector_type(4))) float f32x4;
using bf16 = __hip_bfloat16;

struct bhalf4 { bf16 x, y, z, w; };               // 8 bytes

__device__ __forceinline__ unsigned short f2bfu(float f) {
  bf16 h = __float2bfloat16(f);
  return *reinterpret_cast<unsigned short*>(&h);
}

// ---------------------------------------------------------------------------
// Vectorized transpose + cast: in [B][C][N] fp32 -> out [B][N][C] bf16.
// (unchanged from round-6 passing version)
// ---------------------------------------------------------------------------
template <bool ASQ>
__global__ __launch_bounds__(256) void transpose_cast_v(
    const float* __restrict__ in_all, bf16* __restrict__ out_all,
    float* __restrict__ asq_all) {
  int bz = blockIdx.z;
  const float* in = in_all + (size_t)bz * CH * NN;
  bf16* out = out_all + (size_t)bz * NN * CH;

  __shared__ float tile[64][65];
  __shared__ float sqb[16][64];

  int n0 = blockIdx.x * 64;
  int c0 = blockIdx.y * 64;
  int t = threadIdx.x;
  int nc = t & 15;
  int cr = t >> 4;

  float4 sq4 = make_float4(0.f, 0.f, 0.f, 0.f);
#pragma unroll
  for (int i = 0; i < 4; ++i) {
    int c = cr + i * 16;
    float4 v = *(const float4*)(in + (size_t)(c0 + c) * NN + n0 + nc * 4);
    tile[c][nc * 4 + 0] = v.x;
    tile[c][nc * 4 + 1] = v.y;
    tile[c][nc * 4 + 2] = v.z;
    tile[c][nc * 4 + 3] = v.w;
    if (ASQ) {
      sq4.x += v.x * v.x; sq4.y += v.y * v.y;
      sq4.z += v.z * v.z; sq4.w += v.w * v.w;
    }
  }
  if (ASQ) {
    sqb[cr][nc * 4 + 0] = sq4.x;
    sqb[cr][nc * 4 + 1] = sq4.y;
    sqb[cr][nc * 4 + 2] = sq4.z;
    sqb[cr][nc * 4 + 3] = sq4.w;
  }
  __syncthreads();
  if (ASQ && t < 64) {
    float s = 0.f;
#pragma unroll
    for (int i = 0; i < 16; ++i) s += sqb[i][t];
    atomicAdd(&asq_all[(size_t)bz * NN + n0 + t], s);
  }
  int cchunk = t & 7;
  int nb = t >> 3;
#pragma unroll
  for (int p = 0; p < 2; ++p) {
    int n = nb + p * 32;
    bf16x8 o;
#pragma unroll
    for (int j = 0; j < 8; ++j)
      o[j] = (short)f2bfu(tile[cchunk * 8 + j][n]);
    *(bf16x8*)(out + (size_t)(n0 + n) * CH + c0 + cchunk * 8) = o;
  }
}

// ---------------------------------------------------------------------------
// Plain cast: [B*C*N] fp32 -> bf16 flat.
// ---------------------------------------------------------------------------
__global__ __launch_bounds__(256) void convert_cast(
    const float4* __restrict__ in, bhalf4* __restrict__ out) {
  size_t i = (size_t)blockIdx.x * 256 + threadIdx.x;
  float4 v = in[i];
  bhalf4 o;
  o.x = __float2bfloat16(v.x);
  o.y = __float2bfloat16(v.y);
  o.z = __float2bfloat16(v.z);
  o.w = __float2bfloat16(v.w);
  out[i] = o;
}

// ---------------------------------------------------------------------------
// 256x128 block / 128x64 per-wave / BK=32 / 3-buffer GEMM (C = A * B^T).
// Inputs row-major [rows][K] bf16. 4 waves (2x2). LDS 72 KiB -> 2 blocks/CU.
//
// ROUND-8 CHANGE (one variable): wave tile 64x64 -> 128x64. Rationale: the
// binding resource is LDS bandwidth (m134: ~85 B/cyc/CU). Round-6 geometry
// needed 0.5 KB of LDS reads per MFMA (cap = 930 MFMA cyc / 1700 LDS cyc =
// 55%, measured 31.6%); 128x64 needs 0.375 KB/MFMA and doubles MFMA work
// per wave: cap ~73%. Schedule, swizzle, waits = round-6 proven discipline,
// UNCHANGED:
//   per tile t: {12 ds_read(t); stage(t+2)->buf[(t+2)%3]; BARR; lgkmcnt(0);
//                sched_barrier; 32 MFMA; vmcnt(6) [tail 0]; BARR}
// Race audit identical to round 6 (3-buffer rotation; stage target's prior
// readers drained >= 1 barrier earlier; vmcnt(6) leaves exactly t+2's 6
// loads in flight so t+1's data landed before its reads issue next tile).
//
// MODE 0 (gemm1): e = exp((2*acc - asq[n])/32) -> P bf16 + rowsum atomics.
// MODE 1 (gemm2): acc / rowsum[n] -> fp32 out.
// TM = M/256 tiles, TN = N/128 tiles.
// ---------------------------------------------------------------------------
#define BARR() __builtin_amdgcn_s_barrier()
#define PRIO(x) __builtin_amdgcn_s_setprio(x)
#define LDS_FENCE() do {                                      \
    asm volatile("s_waitcnt lgkmcnt(0)" ::: "memory");        \
    __builtin_amdgcn_sched_barrier(0);                        \
  } while (0)
#define MEM_FENCE() do {                                      \
    asm volatile("" ::: "memory");                            \
    __builtin_amdgcn_sched_barrier(0);                        \
  } while (0)

__device__ __forceinline__ void gload16(const bf16* g, bf16* l) {
  __builtin_amdgcn_global_load_lds(
      (const __attribute__((address_space(1))) void*)g,
      (__attribute__((address_space(3))) void*)l, 16, 0, 0);
}

template <int K, int MODE, int TM, int TN>
__global__ __launch_bounds__(256, 2) void gemm_s3(
    const bf16* __restrict__ Aall, const bf16* __restrict__ Ball,
    bf16* __restrict__ Pall, float* __restrict__ Oall,
    const float* __restrict__ asq_all, float* __restrict__ rsum_all) {
  constexpr int NT = K / 32;           // even for all instantiations
  constexpr int TPB = TM * TN;
  constexpr int NWG = TPB * BATCH;
  constexpr int GRP = (TM < 8) ? TM : 8;

  // XCD-bijective swizzle (NWG % 8 == 0) + L2 grouping (bx-major over
  // by-groups of GRP).
  int lid = blockIdx.x;
  int swz = (lid & 7) * (NWG >> 3) + (lid >> 3);
  int bz  = swz / TPB;
  int rem = swz - bz * TPB;
  int g  = rem / (GRP * TN);
  int r2 = rem - g * (GRP * TN);
  int bx = r2 / GRP;
  int by = g * GRP + (r2 & (GRP - 1));

  const bf16* Ab = Aall + (size_t)bz * TM * 256 * K + (size_t)(by * 256) * K;
  const bf16* Bb = Ball + (size_t)bz * TN * 128 * K + (size_t)(bx * 128) * K;

  __shared__ bf16 As[3][256 * 32];     // 48 KiB
  __shared__ bf16 Bs[3][128 * 32];     // 24 KiB
  bf16* const AsB = &As[0][0];
  bf16* const BsB = &Bs[0][0];

  int tid = threadIdx.x;
  int wv = tid >> 6, lane = tid & 63;
  int fl = lane & 15, quad = lane >> 4;
  int wr = wv >> 1, wc = wv & 1;       // 2x2 waves; wave tile 128x64

  // Staging addresses (pre-swizzled global source; linear LDS dest).
  // A: 1024 cids (4/thread), B: 512 cids (2/thread).
  // cid -> row = cid>>2, lds chunk = cid&3, global chunk = (cid&3)^((row>>1)&3)
  int rA0 = tid >> 2,           cA0 = (tid & 3) ^ ((rA0 >> 1) & 3);
  int rA1 = (256 + tid) >> 2,   cA1 = ((256 + tid) & 3) ^ ((rA1 >> 1) & 3);
  int rA2 = (512 + tid) >> 2,   cA2 = ((512 + tid) & 3) ^ ((rA2 >> 1) & 3);
  int rA3 = (768 + tid) >> 2,   cA3 = ((768 + tid) & 3) ^ ((rA3 >> 1) & 3);
  const bf16* gA0 = Ab + (size_t)rA0 * K + cA0 * 8;
  const bf16* gA1 = Ab + (size_t)rA1 * K + cA1 * 8;
  const bf16* gA2 = Ab + (size_t)rA2 * K + cA2 * 8;
  const bf16* gA3 = Ab + (size_t)rA3 * K + cA3 * 8;
  const bf16* gB0 = Bb + (size_t)rA0 * K + cA0 * 8;   // rows 0..127 ✓ (rA0<128? no!)
  const bf16* gB1 = Bb + (size_t)rA1 * K + cA1 * 8;
  // NOTE: B uses cids 0..511 -> rows 0..127: rA0 = tid>>2 in 0..63, rA1 in
  // 64..127 -- correct coverage of B's 128 rows.
  int lsu = wv * 512;                  // wave-uniform lane-block offset

  // Fragment-read offsets (swizzle chunk ^= (row>>1)&3; lane-constant since
  // mi*16>>1 = mi*8 and wr*128>>1 = wr*64 are both 0 mod 4).
  int kq = (quad ^ ((fl >> 1) & 3)) * 8;
  int aoff = (wr * 128 + fl) * 32 + kq;
  int boff = (wc * 64 + fl) * 32 + kq;

  f32x4 acc[8][4] = {};

#define STAGE2(SB) do {                                                       \
    bf16* da = AsB + (SB) * 8192;                                             \
    bf16* db = BsB + (SB) * 4096;                                             \
    gload16(gA0, da + lsu);        gload16(gA1, da + 2048 + lsu);             \
    gload16(gA2, da + 4096 + lsu); gload16(gA3, da + 6144 + lsu);             \
    gload16(gB0, db + lsu);        gload16(gB1, db + 2048 + lsu);             \
    gA0 += 32; gA1 += 32; gA2 += 32; gA3 += 32; gB0 += 32; gB1 += 32;         \
  } while (0)

  // Prologue: stage tile 0 -> buf0, tile 1 -> buf1; drain tile 0 only.
  STAGE2(0);
  STAGE2(1);
  asm volatile("s_waitcnt vmcnt(6)" ::: "memory");
  BARR();

  int cb = 0, sb = 2;
  for (int t = 0; t < NT; ++t) {
    const bf16* Ac = AsB + cb * 8192;
    const bf16* Bc = BsB + cb * 4096;
    bf16x8 aF[8], bF[4];
#pragma unroll
    for (int mi = 0; mi < 8; ++mi)
      aF[mi] = *(const bf16x8*)(Ac + aoff + mi * 512);
#pragma unroll
    for (int nj = 0; nj < 4; ++nj)
      bF[nj] = *(const bf16x8*)(Bc + boff + nj * 512);

    if (t + 2 < NT) STAGE2(sb);

    BARR();
    asm volatile("s_waitcnt lgkmcnt(0)" ::: "memory");
    __builtin_amdgcn_sched_barrier(0);
    PRIO(1);
#pragma unroll
    for (int mi = 0; mi < 8; ++mi)
#pragma unroll
      for (int nj = 0; nj < 4; ++nj)
        acc[mi][nj] = __builtin_amdgcn_mfma_f32_16x16x32_bf16(
            aF[mi], bF[nj], acc[mi][nj], 0, 0, 0);
    PRIO(0);
    if (t + 2 < NT) {
      asm volatile("s_waitcnt vmcnt(6)" ::: "memory");
    } else {
      asm volatile("s_waitcnt vmcnt(0)" ::: "memory");
    }
    BARR();

    cb = (cb == 2) ? 0 : cb + 1;
    sb = (sb == 2) ? 0 : sb + 1;
  }
#undef STAGE2

  // All staging drained (tail vmcnt(0)) and reads consumed; sync before
  // reusing LDS as epilogue scratch.
  __syncthreads();

  // ---- Epilogue: wave-private 16x64 LDS transpose -> 16B stores ----
  int colbase = bx * 128 + wc * 64;
  int rowg0 = by * 256 + wr * 128;

  if constexpr (MODE == 0) {
    const float* asq = asq_all + (size_t)bz * NN;
    float* rsum = rsum_all + (size_t)bz * NN;
    bf16* P = Pall + (size_t)bz * NN * NN;
    short* scr = (short*)AsB + wv * 1024;   // 16x64 bf16 per wave

    float aq[4];
#pragma unroll
    for (int nj = 0; nj < 4; ++nj) aq[nj] = asq[colbase + nj * 16 + fl];

    float rs[8][4];
#pragma unroll
    for (int mi = 0; mi < 8; ++mi)
#pragma unroll
      for (int r = 0; r < 4; ++r) rs[mi][r] = 0.f;

#pragma unroll
    for (int mi = 0; mi < 8; ++mi) {
#pragma unroll
      for (int nj = 0; nj < 4; ++nj)
#pragma unroll
        for (int r = 0; r < 4; ++r) {
          int row = (quad << 2) + r;
          float e = __expf((2.f * acc[mi][nj][r] - aq[nj]) * 0.03125f);
          rs[mi][r] += e;
          int chunk = (nj * 2 + (fl >> 3)) ^ (row & 7);
          scr[row * 64 + chunk * 8 + (fl & 7)] = (short)f2bfu(e);
        }
      LDS_FENCE();
#pragma unroll
      for (int p = 0; p < 2; ++p) {
        int row = (p << 3) + (lane >> 3);
        int c = lane & 7;
        int chunk = c ^ (row & 7);
        bf16x8 v = *(const bf16x8*)(scr + row * 64 + chunk * 8);
        *(bf16x8*)(P + (size_t)(rowg0 + mi * 16 + row) * NN + colbase + c * 8) = v;
      }
      MEM_FENCE();
    }
#pragma unroll
    for (int mi = 0; mi < 8; ++mi)
#pragma unroll
      for (int r = 0; r < 4; ++r) {
        float v = rs[mi][r];
        v += __shfl_xor(v, 1);
        v += __shfl_xor(v, 2);
        v += __shfl_xor(v, 4);
        v += __shfl_xor(v, 8);
        if (fl == 0)
          atomicAdd(&rsum[rowg0 + mi * 16 + (quad << 2) + r], v);
      }
  } else {
    float* Co = Oall + (size_t)bz * 2 * CH * NN;     // first CV block
    const float* rsum = rsum_all + (size_t)bz * NN;
    float* scr = (float*)AsB + wv * 1024;            // 16x64 f32 per wave

    float inv[4];
#pragma unroll
    for (int nj = 0; nj < 4; ++nj) inv[nj] = 1.f / rsum[colbase + nj * 16 + fl];

#pragma unroll
    for (int mi = 0; mi < 8; ++mi) {
#pragma unroll
      for (int nj = 0; nj < 4; ++nj)
#pragma unroll
        for (int r = 0; r < 4; ++r) {
          int row = (quad << 2) + r;
          int chunk = (nj * 4 + (fl >> 2)) ^ (row & 15);
          scr[row * 64 + chunk * 4 + (fl & 3)] = acc[mi][nj][r] * inv[nj];
        }
      LDS_FENCE();
#pragma unroll
      for (int p = 0; p < 4; ++p) {
        int row = (p << 2) + (lane >> 4);
        int c = lane & 15;
        int chunk = c ^ (row & 15);
        f32x4 v = *(const f32x4*)(scr + row * 64 + chunk * 4);
        *(f32x4*)(Co + (size_t)(rowg0 + mi * 16 + row) * NN + colbase + c * 4) = v;
      }
      MEM_FENCE();
    }
  }
}

// ---------------------------------------------------------------------------
// Copy curr_value into the second half of each batch's output channel block.
// ---------------------------------------------------------------------------
__global__ __launch_bounds__(256) void copy_curr(
    const float4* __restrict__ src, float4* __restrict__ dst) {
  size_t idx = (size_t)blockIdx.x * 256 + threadIdx.x;
  size_t b = idx >> 20;
  size_t r = idx & 1048575;
  dst[b * 2097152 + 1048576 + r] = src[idx];
}

// ---------------------------------------------------------------------------
extern "C" void kernel_launch(void* const* d_in, const int* in_sizes, int n_in,
                              void* d_out, int out_size, void* d_ws, size_t ws_size,
                              hipStream_t stream) {
  const float* prev_key   = (const float*)d_in[0];
  const float* prev_value = (const float*)d_in[1];
  const float* curr_key   = (const float*)d_in[2];
  const float* curr_value = (const float*)d_in[3];
  float* out = (float*)d_out;

  char* ws = (char*)d_ws;
  bf16* P     = (bf16*)(ws);                        // 256 MB [B][N][N]
  bf16* mk_t  = (bf16*)(ws + 268435456u);           //  64 MB [B][N][C]
  bf16* qk_t  = (bf16*)(ws + 335544320u);           //  64 MB [B][N][C]
  bf16* mo_b  = (bf16*)(ws + 402653184u);           //  64 MB [B][C][N]
  float* a_sq = (float*)(ws + 469762048u);          // 128 KB [B][N]
  float* rsum = a_sq + (size_t)BATCH * NN;          // 128 KB [B][N]

  hipMemsetAsync(a_sq, 0, 2ull * BATCH * NN * sizeof(float), stream);

  transpose_cast_v<true><<<dim3(NN / 64, CH / 64, BATCH), 256, 0, stream>>>(
      prev_key, mk_t, a_sq);
  transpose_cast_v<false><<<dim3(NN / 64, CH / 64, BATCH), 256, 0, stream>>>(
      curr_key, qk_t, nullptr);
  convert_cast<<<(size_t)BATCH * CH * NN / 4 / 256, 256, 0, stream>>>(
      (const float4*)prev_value, (bhalf4*)mo_b);

  // GEMM1: ab = qk_t * mk_t^T  (M=N=4096, K=1024), fused exp + rowsum.
  // M tiles = 4096/256 = 16, N tiles = 4096/128 = 32.
  gemm_s3<CH, 0, 16, 32><<<dim3(16 * 32 * BATCH), dim3(256), 0, stream>>>(
      qk_t, mk_t, P, nullptr, a_sq, rsum);

  // GEMM2: mem = mo * P^T  (M=1024, N=4096, K=4096). M tiles = 4, N = 32.
  gemm_s3<NN, 1, 4, 32><<<dim3(4 * 32 * BATCH), dim3(256), 0, stream>>>(
      mo_b, P, nullptr, out, nullptr, rsum);

  copy_curr<<<(size_t)BATCH * CH * NN / 4 / 256, 256, 0, stream>>>(
      (const float4*)curr_value, (float4*)out);
}